// Round 6
// baseline (312.193 us; speedup 1.0000x reference)
//
#include <hip/hip_runtime.h>
#include <math.h>

#define NB    2048
#define NSEG  20
#define MAXIT 48
// LDS chunk layout (8-col): one 32-k chunk = 4 octet-blocks of BLKS shorts.
// BLKS = 64 data shorts (8 cols x 8 k) + 8 pad = 72.
// cols 0..3 = bf16-hi of elems 0..3, cols 4..7 = bf16-lo of elems 0..3.
// Bank math: BLKS*2B = 144B = 36 dw == 4 (mod 32); chunk stride 288*2/4 = 144 == 16 (mod 32).
#define CH    288
#define BLKS  72

typedef __attribute__((ext_vector_type(8))) short bf8_t;
typedef __attribute__((ext_vector_type(4))) float f32x4;

#define cA21 ((float)0.161)
#define cA31 ((float)-0.008480655492356989)
#define cA32 ((float)0.335480655492357)
#define cA41 ((float)2.8971530571054935)
#define cA42 ((float)-6.359448489975075)
#define cA43 ((float)4.3622954328695815)
#define cA51 ((float)5.325864828439257)
#define cA52 ((float)-11.748883564062828)
#define cA53 ((float)7.4955393428898365)
#define cA54 ((float)-0.09249506636175525)
#define cA61 ((float)5.86145544294642)
#define cA62 ((float)-12.92096931784711)
#define cA63 ((float)8.159367898576159)
#define cA64 ((float)-0.071584973281401)
#define cA65 ((float)-0.028269050394068383)
#define cB1  ((float)0.09646076681806523)
#define cB2  ((float)0.01)
#define cB3  ((float)0.4798896504144996)
#define cB4  ((float)1.379008574103742)
#define cB5  ((float)-3.290069515436081)
#define cB6  ((float)2.324710524099774)
#define cE1  ((float)-0.001780011052225777)
#define cE2  ((float)-0.0008164344596567469)
#define cE3  ((float)0.007880878010261995)
#define cE4  ((float)-0.1447110071732629)
#define cE5  ((float)0.5823571654525552)
#define cE6  ((float)-0.45808210592918697)
#define cE7  ((float)0.015151515151515152)

__device__ __forceinline__ void split2(float x, short &hi, short &lo) {
    // x ~= bf16(hi) + bf16(lo), truncation-based (x - hi is exact in fp32)
    unsigned u = __float_as_uint(x);
    hi = (short)(u >> 16);
    float r = x - __uint_as_float(u & 0xFFFF0000u);
    lo = (short)(__float_as_uint(r) >> 16);
}

__device__ __forceinline__ float softplus_f(float x) {
    float t = exp2f(-fabsf(x) * 1.442695040888963f);
    return fmaxf(x, 0.0f) + log2f(1.0f + t) * 0.6931471805599453f;
}

// x + x[lane^4] within each 16-lane row.  xor-4 is not a single rotation:
// ror:4 (0x124) gives lane i <- (i+4)%16, correct for banks 0,2 (i=0-3,8-11);
// ror:12 (0x12C) gives lane i <- (i+12)%16, correct for banks 1,3.
// Compose with bank masks.  Pure VALU.
__device__ __forceinline__ float fold4(float x) {
    int t1 = __builtin_amdgcn_update_dpp(__float_as_int(x), __float_as_int(x),
                                         0x124, 0xF, 0x5, false);
    int t2 = __builtin_amdgcn_update_dpp(t1, __float_as_int(x),
                                         0x12C, 0xF, 0xA, false);
    return x + __int_as_float(t2);
}

// x + x[lane^8] within each 16-lane row (ror:8 == xor-8 on 16 lanes).
__device__ __forceinline__ float fold8(float x) {
    int r = __builtin_amdgcn_update_dpp(__float_as_int(x), __float_as_int(x),
                                        0x128, 0xF, 0xF, false);
    return x + __int_as_float(r);
}

// 256 threads = 4 waves per block, 4 elems per block, grid 512 = 2 blocks/CU.
// Two independent blocks per CU (own barriers, own iteration counts) give each
// SIMD two decoupled instruction streams -> latency chains overlap.
// Weights in per-lane MFMA A-fragments: each wave owns TWO 16-row tiles for
// L1/L2 (rows 32w..32w+31) and one tile for L3 (rows 16w..16w+15).
// B-layout: 8 cols (4 elems hi + lo); lanes with col>=8 read (col&7) duplicates,
// making D cols 8-15 valid copies of 0-7 -> register select works on all lanes.
// State: 1 dim/lane: lane (q,c) owns dim d0=16w+4q+(c>>2) of elem c&3 -> the
// L3 output IS the state layout (kv = f[c>>2], pure register select, no LDS).
// Frag-layout (16x16x32 bf16): A[m=lane&15][k=32c+8*quad+jj]; B[k][n=lane&15];
// C/D: col=lane&15, row=4*quad+reg  (m89-verified).
__global__ __launch_bounds__(256, 2)
void ode_kernel(const float* __restrict__ history,
                const float* __restrict__ W1, const float* __restrict__ b1,
                const float* __restrict__ W2, const float* __restrict__ b2,
                const float* __restrict__ W3, const float* __restrict__ b3,
                float* __restrict__ out)
{
    __shared__ alignas(16) short argB[2 * CH];
    __shared__ alignas(16) short h1B[4 * CH];
    __shared__ alignas(16) short h2B[4 * CH];
    __shared__ float rrP[16];   // [wave][elem] error-norm partials

    const int tid  = threadIdx.x;
    const int wave = tid >> 6, lane = tid & 63;
    const int quad = lane >> 4, col = lane & 15;
    const int rsel = col >> 2, e = col & 3;
    const int d0   = 16 * wave + 4 * quad + rsel;     // this lane's state dim
    const size_t elemIdx = (size_t)blockIdx.x * 4 + e;

    // ---- preload weight A-fragments (bf16 hi/lo); 2 tiles for L1/L2 ----
    bf8_t A1h[2][2], A1l[2][2], A2h[2][4], A2l[2][4], A3h[4], A3l[4];
#pragma unroll
    for (int tt = 0; tt < 2; ++tt) {
        const int row = 16 * (2 * wave + tt) + col;
#pragma unroll
        for (int c = 0; c < 2; ++c) {
            const float* p = W1 + (size_t)row * 64 + 32 * c + 8 * quad;
            bf8_t h, l;
#pragma unroll
            for (int j = 0; j < 8; ++j) { short hs, ls; split2(p[j], hs, ls); h[j] = hs; l[j] = ls; }
            A1h[tt][c] = h; A1l[tt][c] = l;
        }
#pragma unroll
        for (int c = 0; c < 4; ++c) {
            const float* p = W2 + (size_t)row * 128 + 32 * c + 8 * quad;
            bf8_t h, l;
#pragma unroll
            for (int j = 0; j < 8; ++j) { short hs, ls; split2(p[j], hs, ls); h[j] = hs; l[j] = ls; }
            A2h[tt][c] = h; A2l[tt][c] = l;
        }
    }
    {
        const int row = 16 * wave + col;
#pragma unroll
        for (int c = 0; c < 4; ++c) {
            const float* p = W3 + (size_t)row * 128 + 32 * c + 8 * quad;
            bf8_t h, l;
#pragma unroll
            for (int j = 0; j < 8; ++j) { short hs, ls; split2(p[j], hs, ls); h[j] = hs; l[j] = ls; }
            A3h[c] = h; A3l[c] = l;
        }
    }
    f32x4 b1f[2], b2f[2];
#pragma unroll
    for (int tt = 0; tt < 2; ++tt) {
        b1f[tt] = *(const f32x4*)(b1 + 16 * (2 * wave + tt) + 4 * quad);
        b2f[tt] = *(const f32x4*)(b2 + 16 * (2 * wave + tt) + 4 * quad);
    }
    const f32x4 b3f = *(const f32x4*)(b3 + 16 * wave + 4 * quad);

    // B-read offset: cols >=8 duplicate col&7 (keeps D cols 8-15 valid copies)
    const int boff = quad * BLKS + (col & 7) * 8;
    // arg-write index for this lane's (elem, dim)
    const int aidx = (d0 >> 5) * CH + ((d0 >> 3) & 3) * BLKS + e * 8 + (d0 & 7);

    // epilogue for one 16-row tile: fold hi/lo cols, register-select this
    // lane's value (valid on ALL lanes thanks to duplicate cols), softplus,
    // split, store hi (col e) + lo (col e+4).
    auto epiT = [&](f32x4 s, const f32x4& bias, int rowT, short* Bn) {
        float f0 = fold4(s[0]) + bias[0];
        float f1 = fold4(s[1]) + bias[1];
        float f2 = fold4(s[2]) + bias[2];
        float f3 = fold4(s[3]) + bias[3];
        float vlo = (col & 4) ? f1 : f0;
        float vhi = (col & 4) ? f3 : f2;
        float v   = (col & 8) ? vhi : vlo;           // v = f[rsel]
        float p = softplus_f(v);
        short hh, ll; split2(p, hh, ll);
        const int j   = rowT + 4 * quad + rsel;
        const int idx = (j >> 5) * CH + ((j >> 3) & 3) * BLKS + e * 8 + (j & 7);
        Bn[idx]      = hh;
        Bn[idx + 32] = ll;
    };

    // one full MLP eval; args must be in argB.  Returns this lane's k-value
    // (dim d0 of elem e) entirely in-register.  3 barriers, no trailing one.
    auto eval = [&]() -> float {
        __syncthreads();
        {   // L1: argB -> h1B (2 chunks, 2 tiles, 4 independent acc chains)
            f32x4 z = {0.f, 0.f, 0.f, 0.f};
            f32x4 a0h = z, a0l = z, a1h = z, a1l = z;
#pragma unroll
            for (int c = 0; c < 2; ++c) {
                bf8_t b = *(const bf8_t*)(argB + c * CH + boff);
                a0h = __builtin_amdgcn_mfma_f32_16x16x32_bf16(A1h[0][c], b, a0h, 0, 0, 0);
                a0l = __builtin_amdgcn_mfma_f32_16x16x32_bf16(A1l[0][c], b, a0l, 0, 0, 0);
                a1h = __builtin_amdgcn_mfma_f32_16x16x32_bf16(A1h[1][c], b, a1h, 0, 0, 0);
                a1l = __builtin_amdgcn_mfma_f32_16x16x32_bf16(A1l[1][c], b, a1l, 0, 0, 0);
            }
            f32x4 s0, s1;
#pragma unroll
            for (int r = 0; r < 4; ++r) { s0[r] = a0h[r] + a0l[r]; s1[r] = a1h[r] + a1l[r]; }
            epiT(s0, b1f[0], 32 * wave,      h1B);
            epiT(s1, b1f[1], 32 * wave + 16, h1B);
        }
        __syncthreads();
        {   // L2: h1B -> h2B (4 chunks split into 2 pairs -> chain length 2)
            f32x4 z = {0.f, 0.f, 0.f, 0.f};
            f32x4 aA[2][2] = {{z, z}, {z, z}}, aB[2][2] = {{z, z}, {z, z}};
#pragma unroll
            for (int c = 0; c < 2; ++c) {
                bf8_t b = *(const bf8_t*)(h1B + c * CH + boff);
                aA[0][0] = __builtin_amdgcn_mfma_f32_16x16x32_bf16(A2h[0][c], b, aA[0][0], 0, 0, 0);
                aA[0][1] = __builtin_amdgcn_mfma_f32_16x16x32_bf16(A2l[0][c], b, aA[0][1], 0, 0, 0);
                aA[1][0] = __builtin_amdgcn_mfma_f32_16x16x32_bf16(A2h[1][c], b, aA[1][0], 0, 0, 0);
                aA[1][1] = __builtin_amdgcn_mfma_f32_16x16x32_bf16(A2l[1][c], b, aA[1][1], 0, 0, 0);
            }
#pragma unroll
            for (int c = 2; c < 4; ++c) {
                bf8_t b = *(const bf8_t*)(h1B + c * CH + boff);
                aB[0][0] = __builtin_amdgcn_mfma_f32_16x16x32_bf16(A2h[0][c], b, aB[0][0], 0, 0, 0);
                aB[0][1] = __builtin_amdgcn_mfma_f32_16x16x32_bf16(A2l[0][c], b, aB[0][1], 0, 0, 0);
                aB[1][0] = __builtin_amdgcn_mfma_f32_16x16x32_bf16(A2h[1][c], b, aB[1][0], 0, 0, 0);
                aB[1][1] = __builtin_amdgcn_mfma_f32_16x16x32_bf16(A2l[1][c], b, aB[1][1], 0, 0, 0);
            }
            f32x4 s0, s1;
#pragma unroll
            for (int r = 0; r < 4; ++r) {
                s0[r] = (aA[0][0][r] + aA[0][1][r]) + (aB[0][0][r] + aB[0][1][r]);
                s1[r] = (aA[1][0][r] + aA[1][1][r]) + (aB[1][0][r] + aB[1][1][r]);
            }
            epiT(s0, b2f[0], 32 * wave,      h2B);
            epiT(s1, b2f[1], 32 * wave + 16, h2B);
        }
        __syncthreads();
        {   // L3: h2B -> in-register kv (1 tile/wave, rows 16w.. == state rows)
            f32x4 z = {0.f, 0.f, 0.f, 0.f};
            f32x4 pAh = z, pAl = z, pBh = z, pBl = z;
#pragma unroll
            for (int c = 0; c < 2; ++c) {
                bf8_t b = *(const bf8_t*)(h2B + c * CH + boff);
                pAh = __builtin_amdgcn_mfma_f32_16x16x32_bf16(A3h[c], b, pAh, 0, 0, 0);
                pAl = __builtin_amdgcn_mfma_f32_16x16x32_bf16(A3l[c], b, pAl, 0, 0, 0);
            }
#pragma unroll
            for (int c = 2; c < 4; ++c) {
                bf8_t b = *(const bf8_t*)(h2B + c * CH + boff);
                pBh = __builtin_amdgcn_mfma_f32_16x16x32_bf16(A3h[c], b, pBh, 0, 0, 0);
                pBl = __builtin_amdgcn_mfma_f32_16x16x32_bf16(A3l[c], b, pBl, 0, 0, 0);
            }
            // fold ALL regs first, select after (round-4 lesson)
            float f0 = fold4((pAh[0] + pAl[0]) + (pBh[0] + pBl[0])) + b3f[0];
            float f1 = fold4((pAh[1] + pAl[1]) + (pBh[1] + pBl[1])) + b3f[1];
            float f2 = fold4((pAh[2] + pAl[2]) + (pBh[2] + pBl[2])) + b3f[2];
            float f3 = fold4((pAh[3] + pAl[3]) + (pBh[3] + pBl[3])) + b3f[3];
            float vlo = (col & 4) ? f1 : f0;
            float vhi = (col & 4) ? f3 : f2;
            return (col & 8) ? vhi : vlo;            // kv = f[rsel] + b3[d0]
        }
    };

    auto argw = [&](float a) {
        short hh, ll; split2(a, hh, ll);
        argB[aidx]      = hh;
        argB[aidx + 32] = ll;
    };

    // ---- state: 1 dim per lane (all 256 lanes carry state) ----
    float y  = history[(elemIdx * 15 + 14) * 64 + d0];
    float dt = 0.1f;
    float k1, k2, k3, k4, k5, k6;

    // initial k1 = f(y)  (FSAL thereafter)
    argw(y);
    k1 = eval();

#pragma unroll 1
    for (int seg = 1; seg <= NSEG; ++seg) {
        const float t1 = (float)seg;
        float t = t1 - 1.0f;
        bool done = false;

#pragma unroll 1
        for (int it = 0; it < MAXIT; ++it) {
            const float dt_c = fminf(dt, t1 - t);
            const float h = dt_c;
            float y5v = 0.f, k7v = 0.f;

#pragma unroll 1
            for (int st = 2; st <= 7; ++st) {
                float sum;
                switch (st) {
                    case 2: sum = cA21 * k1; break;
                    case 3: sum = fmaf(cA31, k1, cA32 * k2); break;
                    case 4: sum = fmaf(cA41, k1, fmaf(cA42, k2, cA43 * k3)); break;
                    case 5: sum = fmaf(cA51, k1, fmaf(cA52, k2, fmaf(cA53, k3, cA54 * k4))); break;
                    case 6: sum = fmaf(cA61, k1, fmaf(cA62, k2, fmaf(cA63, k3, fmaf(cA64, k4, cA65 * k5)))); break;
                    default: sum = fmaf(cB1, k1, fmaf(cB2, k2, fmaf(cB3, k3, fmaf(cB4, k4, fmaf(cB5, k5, cB6 * k6))))); break;
                }
                float arg = fmaf(h, sum, y);
                if (st == 7) y5v = arg;
                argw(arg);
                float kv = eval();
                switch (st) {
                    case 2: k2 = kv; break;
                    case 3: k3 = kv; break;
                    case 4: k4 = kv; break;
                    case 5: k5 = kv; break;
                    case 6: k6 = kv; break;
                    default: k7v = kv; break;
                }
            }

            // error norm: 1-dim partial -> in-wave reduce (q via shfl, rsel via
            // fold4+fold8; all symmetric, no pre-select) -> cross-wave via rrP
            float esum = fmaf(cE1, k1, fmaf(cE2, k2, fmaf(cE3, k3,
                         fmaf(cE4, k4, fmaf(cE5, k5, fmaf(cE6, k6, cE7 * k7v))))));
            float err = h * esum;
            float sc = fmaf(1e-3f, fmaxf(fabsf(y), fabsf(y5v)), 1e-6f);
            float r = err / sc;
            float rr = r * r;
            rr += __shfl_xor(rr, 16, 64);   // sum quad bit0
            rr += __shfl_xor(rr, 32, 64);   // sum quad bit1
            rr = fold4(rr);                 // sum rsel bit0
            rr = fold8(rr);                 // sum rsel bit1
            if (lane < 4) rrP[wave * 4 + lane] = rr;   // lane = elem
            __syncthreads();
            float rs = ((rrP[e] + rrP[4 + e]) + rrP[8 + e]) + rrP[12 + e];
            float en = sqrtf(rs * (1.0f / 64.0f));

            bool accept = (en <= 1.0f) && !done;
            float fac = 0.9f * exp2f(-0.2f * log2f(fmaxf(en, 1e-10f)));
            fac = fminf(fmaxf(fac, 0.2f), 10.0f);

            if (accept) { t += dt_c; y = y5v; k1 = k7v; }   // FSAL: f(y_new) = k7
            if (!done) dt = dt_c * fac;
            done = done || (t >= t1 - 1e-8f);
            if (__all(done)) break;
        }

        out[(elemIdx * NSEG + (seg - 1)) * 64 + d0] = y;
    }
}

extern "C" void kernel_launch(void* const* d_in, const int* in_sizes, int n_in,
                              void* d_out, int out_size, void* d_ws, size_t ws_size,
                              hipStream_t stream) {
    const float* history = (const float*)d_in[0];
    const float* W1 = (const float*)d_in[1];
    const float* b1 = (const float*)d_in[2];
    const float* W2 = (const float*)d_in[3];
    const float* b2 = (const float*)d_in[4];
    const float* W3 = (const float*)d_in[5];
    const float* b3 = (const float*)d_in[6];
    float* out = (float*)d_out;

    ode_kernel<<<dim3(NB / 4), dim3(256), 0, stream>>>(history, W1, b1, W2, b2, W3, b3, out);
}

// Round 7
// 299.179 us; speedup vs baseline: 1.0435x; 1.0435x over previous
//
#include <hip/hip_runtime.h>
#include <math.h>

#define NB    2048
#define NSEG  20
#define MAXIT 48
// LDS chunk layout: one 32-k chunk = 4 octet-blocks of BLKS shorts.
// BLKS = 128 data shorts (16 cols x 8 k) + 8 pad shorts = 136.
// cols 0..7 = bf16-hi of elems 0..7, cols 8..15 = bf16-lo of elems 0..7.
// Bank math: BLKS*2B = 272B = 68 dwords == 4 (mod 32); chunk stride 544*2/4 = 272 == 16 (mod 32).
#define CH    544
#define BLKS  136

typedef __attribute__((ext_vector_type(8))) short bf8_t;
typedef __attribute__((ext_vector_type(4))) float f32x4;

#define cA21 ((float)0.161)
#define cA31 ((float)-0.008480655492356989)
#define cA32 ((float)0.335480655492357)
#define cA41 ((float)2.8971530571054935)
#define cA42 ((float)-6.359448489975075)
#define cA43 ((float)4.3622954328695815)
#define cA51 ((float)5.325864828439257)
#define cA52 ((float)-11.748883564062828)
#define cA53 ((float)7.4955393428898365)
#define cA54 ((float)-0.09249506636175525)
#define cA61 ((float)5.86145544294642)
#define cA62 ((float)-12.92096931784711)
#define cA63 ((float)8.159367898576159)
#define cA64 ((float)-0.071584973281401)
#define cA65 ((float)-0.028269050394068383)
#define cB1  ((float)0.09646076681806523)
#define cB2  ((float)0.01)
#define cB3  ((float)0.4798896504144996)
#define cB4  ((float)1.379008574103742)
#define cB5  ((float)-3.290069515436081)
#define cB6  ((float)2.324710524099774)
#define cE1  ((float)-0.001780011052225777)
#define cE2  ((float)-0.0008164344596567469)
#define cE3  ((float)0.007880878010261995)
#define cE4  ((float)-0.1447110071732629)
#define cE5  ((float)0.5823571654525552)
#define cE6  ((float)-0.45808210592918697)
#define cE7  ((float)0.015151515151515152)

#define KL2E 1.4426950408889634f
#define KLN2 0.6931471805599453f

__device__ __forceinline__ void split2(float x, short &hi, short &lo) {
    // x ~= bf16(hi) + bf16(lo), truncation-based (x - hi is exact in fp32)
    unsigned u = __float_as_uint(x);
    hi = (short)(u >> 16);
    float r = x - __uint_as_float(u & 0xFFFF0000u);
    lo = (short)(__float_as_uint(r) >> 16);
}

// rne bf16 (preload-only; halves hi error vs truncation)
__device__ __forceinline__ short bfr(float x) {
    unsigned u = __float_as_uint(x);
    unsigned r = u + 0x7FFFu + ((u >> 16) & 1u);
    return (short)(r >> 16);
}
__device__ __forceinline__ void splitw(float x, short &hi, short &lo) {
    hi = bfr(x);
    float hf = __uint_as_float(((unsigned)(unsigned short)hi) << 16);
    lo = bfr(x - hf);
}

// scaled softplus: with z = log2e*x, sp2(z) = log2e*softplus(x).
// 5 ops: exp2(-|z|) [input modifiers free], add, log2, max, add.
__device__ __forceinline__ float sp2(float z) {
    float t = exp2f(-fabsf(z));
    return fmaxf(z, 0.0f) + log2f(1.0f + t);
}

__device__ __forceinline__ unsigned pk(short a, short b) {
    return ((unsigned)(unsigned short)a) | (((unsigned)(unsigned short)b) << 16);
}

// pack hi16(a) | hi16(b)<<16 in ONE v_perm_b32:
// sel bytes: D.b0=a.b2(sel 2), D.b1=a.b3(3), D.b2=b.b2(src0 -> 6), D.b3=b.b3(7)
__device__ __forceinline__ unsigned pk_hi(float a, float b) {
    return __builtin_amdgcn_perm(__float_as_uint(b), __float_as_uint(a), 0x07060302u);
}
__device__ __forceinline__ float trunc16(float x) {
    return __uint_as_float(__float_as_uint(x) & 0xFFFF0000u);
}

// x + x[lane^8] within each 16-lane row: DPP row_ror:8 (0x128).  Pure VALU.
// NOTE: apply BEFORE any esel-dependent register select (round-4 lesson).
__device__ __forceinline__ float fold8(float x) {
    int r = __builtin_amdgcn_update_dpp(__float_as_int(x), __float_as_int(x),
                                        0x128, 0xF, 0xF, false);
    return x + __int_as_float(r);
}

// 512 threads = 8 waves; block processes 8 elements in lockstep.
// Weights live in per-lane MFMA A-fragments (bf16 hi/lo, rne split) with
// softplus prescaling folded in: W1,b1,b2 scaled by log2e; W3 by ln2; W2
// unchanged (ln2*log2e = 1).  Hidden activations stored as s = log2e*h.
// Acts ping-pong through LDS in MFMA B-fragment layout with hi/lo packed into
// the 16 columns: col e = hi(elem e), col e+8 = lo(elem e).  Two MFMAs/chunk.
// RK state in MFMA D-layout on waves 0-3 (2 dims/lane); L3 output consumed
// in-register.  Waves 4-7 are pure GEMM workers (deterministic replicas).
// Frag-layout (16x16x32 bf16): A[m=lane&15][k=32c+8*quad+jj]; B[k][n=lane&15];
// C/D: col=lane&15, row=4*quad+reg  (m89-verified).
__global__ __launch_bounds__(512)
void ode_kernel(const float* __restrict__ history,
                const float* __restrict__ W1, const float* __restrict__ b1,
                const float* __restrict__ W2, const float* __restrict__ b2,
                const float* __restrict__ W3, const float* __restrict__ b3,
                float* __restrict__ out)
{
    __shared__ alignas(16) short argB[2 * CH];
    __shared__ alignas(16) short h1B[4 * CH];
    __shared__ alignas(16) short h2B[4 * CH];
    __shared__ float rrP[32];   // [wave<4][elem] error-norm partials

    const int tid  = threadIdx.x;
    const int wave = tid >> 6, lane = tid & 63;
    const int quad = lane >> 4, col = lane & 15;
    const int jb   = 16 * wave + 4 * quad;       // this lane's D-row base (j)

    // ---- preload weight A-fragments (rne bf16 hi/lo, prescaled) ----
    bf8_t A1h[2], A1l[2], A2h[4], A2l[4], A3h[4], A3l[4];
#pragma unroll
    for (int c = 0; c < 2; ++c) {
        const float* p = W1 + (size_t)(16 * wave + col) * 64 + 32 * c + 8 * quad;
        bf8_t h, l;
#pragma unroll
        for (int j = 0; j < 8; ++j) { short hs, ls; splitw(p[j] * KL2E, hs, ls); h[j] = hs; l[j] = ls; }
        A1h[c] = h; A1l[c] = l;
    }
#pragma unroll
    for (int c = 0; c < 4; ++c) {
        const float* p = W2 + (size_t)(16 * wave + col) * 128 + 32 * c + 8 * quad;
        bf8_t h, l;
#pragma unroll
        for (int j = 0; j < 8; ++j) { short hs, ls; splitw(p[j], hs, ls); h[j] = hs; l[j] = ls; }
        A2h[c] = h; A2l[c] = l;
    }
    // state mapping (waves 0-3): esel splits the 4 D-rows into two 2-row halves
    const int esel = col >> 3;
    const int e    = col & 7;
    const int d0   = 16 * wave + 4 * quad + 2 * esel;   // meaningful for wave<4
    const size_t elemIdx = (size_t)(blockIdx.x * 8 + e);

    float b3v0 = 0.f, b3v1 = 0.f;
    if (wave < 4) {
#pragma unroll
        for (int c = 0; c < 4; ++c) {
            const float* p = W3 + (size_t)(16 * wave + col) * 128 + 32 * c + 8 * quad;
            bf8_t h, l;
#pragma unroll
            for (int j = 0; j < 8; ++j) { short hs, ls; splitw(p[j] * KLN2, hs, ls); h[j] = hs; l[j] = ls; }
            A3h[c] = h; A3l[c] = l;
        }
        b3v0 = b3[d0]; b3v1 = b3[d0 + 1];
    } else {
        bf8_t z = {0, 0, 0, 0, 0, 0, 0, 0};
#pragma unroll
        for (int c = 0; c < 4; ++c) { A3h[c] = z; A3l[c] = z; }
    }
    f32x4 b1f, b2f;
    {
        f32x4 t1v = *(const f32x4*)(b1 + jb);
        f32x4 t2v = *(const f32x4*)(b2 + jb);
#pragma unroll
        for (int r = 0; r < 4; ++r) { b1f[r] = t1v[r] * KL2E; b2f[r] = t2v[r] * KL2E; }
    }

    // arg-write index (waves 0-3): same formula as epidx, rows = dims 0..63
    const int ai = (d0 >> 5) * CH + ((d0 >> 3) & 3) * BLKS + e * 8 + (d0 & 7);

    // epilogue mapping: lane (quad, col) handles elem col&7, rows j0, j0+1
    const int j0    = 16 * wave + 4 * quad + 2 * esel;
    const int epidx = (j0 >> 5) * CH + ((j0 >> 3) & 3) * BLKS + e * 8 + (j0 & 7);

    // B-read offset: full 16 distinct columns (8 hi + 8 lo)
    const int boff = quad * BLKS + col * 8;

    // all-lane epilogue: fold hi/lo columns (ALL regs, then select), sp2,
    // perm-pack back to hi/lo bf16 and store both column groups.
    auto epi = [&](f32x4 s, f32x4 bias, short* Bn) {
        float t0 = fold8(s[0]) + bias[0];
        float t1 = fold8(s[1]) + bias[1];
        float t2 = fold8(s[2]) + bias[2];
        float t3 = fold8(s[3]) + bias[3];
        float x0 = esel ? t2 : t0;
        float x1 = esel ? t3 : t1;
        float p0 = sp2(x0), p1 = sp2(x1);
        unsigned hw = pk_hi(p0, p1);
        float r0 = p0 - trunc16(p0);
        float r1 = p1 - trunc16(p1);
        unsigned lw = pk_hi(r0, r1);
        *(unsigned*)(Bn + epidx)      = hw;   // rows j0, j0+1 adjacent shorts
        *(unsigned*)(Bn + epidx + 64) = lw;   // lo column group (col+8)
    };

    // one full MLP eval; args must be in argB.  L3 result (this lane's 2 dims)
    // returned in kv0/kv1 for waves 0-3.  3 barriers, no trailing one.
    auto eval = [&](float &kv0, float &kv1) {
        __syncthreads();
        {   // L1: 4 independent chain-1 accumulators
            bf8_t b0 = *(const bf8_t*)(argB + boff);
            bf8_t b1c = *(const bf8_t*)(argB + CH + boff);
            f32x4 z = {0.f, 0.f, 0.f, 0.f};
            f32x4 ah0 = __builtin_amdgcn_mfma_f32_16x16x32_bf16(A1h[0], b0,  z, 0, 0, 0);
            f32x4 al0 = __builtin_amdgcn_mfma_f32_16x16x32_bf16(A1l[0], b0,  z, 0, 0, 0);
            f32x4 ah1 = __builtin_amdgcn_mfma_f32_16x16x32_bf16(A1h[1], b1c, z, 0, 0, 0);
            f32x4 al1 = __builtin_amdgcn_mfma_f32_16x16x32_bf16(A1l[1], b1c, z, 0, 0, 0);
            f32x4 s;
#pragma unroll
            for (int r = 0; r < 4; ++r) s[r] = (ah0[r] + al0[r]) + (ah1[r] + al1[r]);
            epi(s, b1f, h1B);
        }
        __syncthreads();
        {   // L2: 4 chunks as 2 chain-2 pairs
            f32x4 z = {0.f, 0.f, 0.f, 0.f};
            f32x4 aA0 = z, aA1 = z, aB0 = z, aB1 = z;
#pragma unroll
            for (int c = 0; c < 2; ++c) {
                bf8_t b = *(const bf8_t*)(h1B + c * CH + boff);
                aA0 = __builtin_amdgcn_mfma_f32_16x16x32_bf16(A2h[c], b, aA0, 0, 0, 0);
                aA1 = __builtin_amdgcn_mfma_f32_16x16x32_bf16(A2l[c], b, aA1, 0, 0, 0);
            }
#pragma unroll
            for (int c = 2; c < 4; ++c) {
                bf8_t b = *(const bf8_t*)(h1B + c * CH + boff);
                aB0 = __builtin_amdgcn_mfma_f32_16x16x32_bf16(A2h[c], b, aB0, 0, 0, 0);
                aB1 = __builtin_amdgcn_mfma_f32_16x16x32_bf16(A2l[c], b, aB1, 0, 0, 0);
            }
            f32x4 s;
#pragma unroll
            for (int r = 0; r < 4; ++r) s[r] = (aA0[r] + aA1[r]) + (aB0[r] + aB1[r]);
            epi(s, b2f, h2B);
        }
        __syncthreads();
        if (wave < 4) {
            // L3: 4 independent chains; fold FIRST, select after (round-4 lesson)
            f32x4 z = {0.f, 0.f, 0.f, 0.f};
            f32x4 pAh = z, pAl = z, pBh = z, pBl = z;
#pragma unroll
            for (int c = 0; c < 2; ++c) {
                bf8_t b = *(const bf8_t*)(h2B + c * CH + boff);
                pAh = __builtin_amdgcn_mfma_f32_16x16x32_bf16(A3h[c], b, pAh, 0, 0, 0);
                pAl = __builtin_amdgcn_mfma_f32_16x16x32_bf16(A3l[c], b, pAl, 0, 0, 0);
            }
#pragma unroll
            for (int c = 2; c < 4; ++c) {
                bf8_t b = *(const bf8_t*)(h2B + c * CH + boff);
                pBh = __builtin_amdgcn_mfma_f32_16x16x32_bf16(A3h[c], b, pBh, 0, 0, 0);
                pBl = __builtin_amdgcn_mfma_f32_16x16x32_bf16(A3l[c], b, pBl, 0, 0, 0);
            }
            float f0 = fold8((pAh[0] + pAl[0]) + (pBh[0] + pBl[0]));
            float f1 = fold8((pAh[1] + pAl[1]) + (pBh[1] + pBl[1]));
            float f2 = fold8((pAh[2] + pAl[2]) + (pBh[2] + pBl[2]));
            float f3 = fold8((pAh[3] + pAl[3]) + (pBh[3] + pBl[3]));
            kv0 = (esel ? f2 : f0) + b3v0;
            kv1 = (esel ? f3 : f1) + b3v1;
        }
    };

    auto argw = [&](float a0, float a1) {
        // args keep truncation split (residual exact in fp32)
        unsigned hw = pk_hi(a0, a1);
        float r0 = a0 - trunc16(a0);
        float r1 = a1 - trunc16(a1);
        unsigned lw = pk_hi(r0, r1);
        *(unsigned*)(argB + ai)      = hw;
        *(unsigned*)(argB + ai + 64) = lw;
    };

    // ---- state (waves 0-3, D-layout): 2 dims per lane ----
    float y0 = 0.f, y1 = 0.f;
    float dt = 0.1f;              // tracked by ALL waves (deterministic replicas)
    float k1a = 0.f, k1b = 0.f, k2a, k2b, k3a, k3b, k4a, k4b, k5a, k5b, k6a, k6b;

    // initial k1 = f(y)  (FSAL thereafter)
    if (wave < 4) {
        float2 yy = *(const float2*)(history + (elemIdx * 15 + 14) * 64 + d0);
        y0 = yy.x; y1 = yy.y;
        argw(y0, y1);
    }
    eval(k1a, k1b);

#pragma unroll 1
    for (int seg = 1; seg <= NSEG; ++seg) {
        const float t1 = (float)seg;
        float t = t1 - 1.0f;
        bool done = false;

#pragma unroll 1
        for (int it = 0; it < MAXIT; ++it) {
            const float dt_c = fminf(dt, t1 - t);
            const float h = dt_c;
            float y50 = 0.f, y51 = 0.f, k7a = 0.f, k7b = 0.f;

#pragma unroll 1
            for (int st = 2; st <= 7; ++st) {
                if (wave < 4) {
                    float sum0, sum1;
                    switch (st) {
                        case 2: sum0 = cA21 * k1a;
                                sum1 = cA21 * k1b; break;
                        case 3: sum0 = fmaf(cA31, k1a, cA32 * k2a);
                                sum1 = fmaf(cA31, k1b, cA32 * k2b); break;
                        case 4: sum0 = fmaf(cA41, k1a, fmaf(cA42, k2a, cA43 * k3a));
                                sum1 = fmaf(cA41, k1b, fmaf(cA42, k2b, cA43 * k3b)); break;
                        case 5: sum0 = fmaf(cA51, k1a, fmaf(cA52, k2a, fmaf(cA53, k3a, cA54 * k4a)));
                                sum1 = fmaf(cA51, k1b, fmaf(cA52, k2b, fmaf(cA53, k3b, cA54 * k4b))); break;
                        case 6: sum0 = fmaf(cA61, k1a, fmaf(cA62, k2a, fmaf(cA63, k3a, fmaf(cA64, k4a, cA65 * k5a))));
                                sum1 = fmaf(cA61, k1b, fmaf(cA62, k2b, fmaf(cA63, k3b, fmaf(cA64, k4b, cA65 * k5b)))); break;
                        default: sum0 = fmaf(cB1, k1a, fmaf(cB2, k2a, fmaf(cB3, k3a, fmaf(cB4, k4a, fmaf(cB5, k5a, cB6 * k6a)))));
                                 sum1 = fmaf(cB1, k1b, fmaf(cB2, k2b, fmaf(cB3, k3b, fmaf(cB4, k4b, fmaf(cB5, k5b, cB6 * k6b))))); break;
                    }
                    float arg0 = fmaf(h, sum0, y0);
                    float arg1 = fmaf(h, sum1, y1);
                    if (st == 7) { y50 = arg0; y51 = arg1; }
                    argw(arg0, arg1);
                }
                float kv0 = 0.f, kv1 = 0.f;
                eval(kv0, kv1);
                if (wave < 4) {
                    switch (st) {
                        case 2: k2a = kv0; k2b = kv1; break;
                        case 3: k3a = kv0; k3b = kv1; break;
                        case 4: k4a = kv0; k4b = kv1; break;
                        case 5: k5a = kv0; k5b = kv1; break;
                        case 6: k6a = kv0; k6b = kv1; break;
                        default: k7a = kv0; k7b = kv1; break;
                    }
                }
            }

            // error norm: per-lane 2-dim partial -> wave partial -> LDS -> all
            float rr2 = 0.f;
            if (wave < 4) {
                float es0 = fmaf(cE1, k1a, fmaf(cE2, k2a, fmaf(cE3, k3a,
                            fmaf(cE4, k4a, fmaf(cE5, k5a, fmaf(cE6, k6a, cE7 * k7a))))));
                float es1 = fmaf(cE1, k1b, fmaf(cE2, k2b, fmaf(cE3, k3b,
                            fmaf(cE4, k4b, fmaf(cE5, k5b, fmaf(cE6, k6b, cE7 * k7b))))));
                float err0 = h * es0, err1 = h * es1;
                float sc0 = fmaf(1e-3f, fmaxf(fabsf(y0), fabsf(y50)), 1e-6f);
                float sc1 = fmaf(1e-3f, fmaxf(fabsf(y1), fabsf(y51)), 1e-6f);
                float r0 = err0 / sc0, r1 = err1 / sc1;
                rr2 = fmaf(r0, r0, r1 * r1);
            }
            rr2 += __shfl_xor(rr2, 16, 64);   // sum quad bit0
            rr2 += __shfl_xor(rr2, 32, 64);   // sum quad bit1
            rr2 = fold8(rr2);                 // sum esel halves (symmetric, no select)
            if (wave < 4 && lane < 8) rrP[wave * 8 + lane] = rr2;  // lane = elem
            __syncthreads();
            float rs = ((rrP[e] + rrP[8 + e]) + rrP[16 + e]) + rrP[24 + e];
            float en = sqrtf(rs * (1.0f / 64.0f));

            bool accept = (en <= 1.0f) && !done;
            float fac = 0.9f * exp2f(-0.2f * log2f(fmaxf(en, 1e-10f)));
            fac = fminf(fmaxf(fac, 0.2f), 10.0f);

            if (wave < 4 && accept) { y0 = y50; y1 = y51; k1a = k7a; k1b = k7b; }  // FSAL
            if (accept) t += dt_c;
            if (!done) dt = dt_c * fac;
            done = done || (t >= t1 - 1e-8f);
            if (__all(done)) break;
        }

        if (wave < 4) {
            float2 yy; yy.x = y0; yy.y = y1;
            *(float2*)(out + (elemIdx * NSEG + (seg - 1)) * 64 + d0) = yy;
        }
    }
}

extern "C" void kernel_launch(void* const* d_in, const int* in_sizes, int n_in,
                              void* d_out, int out_size, void* d_ws, size_t ws_size,
                              hipStream_t stream) {
    const float* history = (const float*)d_in[0];
    const float* W1 = (const float*)d_in[1];
    const float* b1 = (const float*)d_in[2];
    const float* W2 = (const float*)d_in[3];
    const float* b2 = (const float*)d_in[4];
    const float* W3 = (const float*)d_in[5];
    const float* b3 = (const float*)d_in[6];
    float* out = (float*)d_out;

    ode_kernel<<<dim3(NB / 8), dim3(512), 0, stream>>>(history, W1, b1, W2, b2, W3, b3, out);
}